// Round 9
// baseline (142.112 us; speedup 1.0000x reference)
//
#include <hip/hip_runtime.h>
#include <math.h>

namespace {
constexpr int BN = 512, HH = 64, WW = 128, CC = 3;
constexpr int OHH = 13, OWW = 26;
constexpr int NPOS = OHH * OWW;   // 338
constexpr int PCH = 26;           // pos per theta1 chunk
constexpr int NPC = NPOS / PCH;   // 13
}

// ---------------------------------------------------------------------------
// K1: fused LocNet front end + fc0 partial.
// Per thread (pos,b): avgpool+conv0+relu and conv1+relu entirely in registers,
// then immediately matvec the 64 feat values into hacc[32] using fc0 rows
// pos*64+ch. pos = blockIdx>>1 is PROVABLY uniform -> fc0/conv weight loads
// scalarize to s_load. Output: part[pos][n][b] (b innermost -> full-line
// 256B wave stores). featT never materialized.
// ---------------------------------------------------------------------------
__global__ __launch_bounds__(256) void k_locnet(const float* __restrict__ x,
                                                const float* __restrict__ w0,
                                                const float* __restrict__ w1,
                                                const float* __restrict__ fw0,
                                                float* __restrict__ part) {
  const int pos = blockIdx.x >> 1;                       // uniform per block
  const int b = ((blockIdx.x & 1) << 8) + threadIdx.x;   // 0..511
  const int oh = pos / 26;
  const int ow = pos - oh * 26;
  const float* xb = x + (size_t)b * (HH * WW * CC);

  // footprint rows oh*5-1 .. oh*5+4, 15 consecutive floats per row
  float xv[6][15];
  if (ow > 0 && ow < OWW - 1) {
    // interior: no column clipping; row validity is uniform
#pragma unroll
    for (int ri = 0; ri < 6; ++ri) {
      const int gr = oh * 5 - 1 + ri;
      if (gr >= 0 && gr < HH) {
        const float* rp = xb + gr * (WW * CC) + (ow * 5 - 1) * 3;
        const float4 q0 = *(const float4*)(rp);
        const float4 q1 = *(const float4*)(rp + 4);
        const float4 q2 = *(const float4*)(rp + 8);
        const float4 q3 = *(const float4*)(rp + 12);  // elem 15 unused
        xv[ri][0] = q0.x; xv[ri][1] = q0.y; xv[ri][2] = q0.z; xv[ri][3] = q0.w;
        xv[ri][4] = q1.x; xv[ri][5] = q1.y; xv[ri][6] = q1.z; xv[ri][7] = q1.w;
        xv[ri][8] = q2.x; xv[ri][9] = q2.y; xv[ri][10] = q2.z; xv[ri][11] = q2.w;
        xv[ri][12] = q3.x; xv[ri][13] = q3.y; xv[ri][14] = q3.z;
      } else {
#pragma unroll
        for (int c = 0; c < 15; ++c) xv[ri][c] = 0.f;
      }
    }
  } else {
    // edge columns (ow==0 or ow==25): per-element clip path (uniform branch)
#pragma unroll
    for (int ri = 0; ri < 6; ++ri) {
      const int gr = oh * 5 - 1 + ri;
      const int grc = min(max(gr, 0), HH - 1);
      const bool rv = (gr >= 0) & (gr <= HH - 1);
      const float* rowp = xb + grc * (WW * CC);
#pragma unroll
      for (int pj = 0; pj < 5; ++pj) {
        const int gc = ow * 5 - 1 + pj;
        const int gcc = min(max(gc, 0), WW - 1);
        const bool v = rv & (gc >= 0) & (gc <= WW - 1);
        const float* pp = rowp + gcc * CC;
        const float f0 = pp[0], f1 = pp[1], f2 = pp[2];
        xv[ri][pj * 3 + 0] = v ? f0 : 0.f;
        xv[ri][pj * 3 + 1] = v ? f1 : 0.f;
        xv[ri][pj * 3 + 2] = v ? f2 : 0.f;
      }
    }
  }

  float hacc[32];
#pragma unroll
  for (int n = 0; n < 32; ++n) hacc[n] = 0.f;

  // ---- conv1 (raw x) -> feat ch 32..63, fused matvec into hacc ----
#pragma unroll 1
  for (int qg = 0; qg < 8; ++qg) {
    float a0 = 0.f, a1 = 0.f, a2 = 0.f, a3 = 0.f;
#pragma unroll
    for (int kh = 0; kh < 5; ++kh)
#pragma unroll
      for (int kw = 0; kw < 5; ++kw)
#pragma unroll
        for (int ic = 0; ic < 3; ++ic) {
          const float pv = xv[kh + 1][kw * 3 + ic];
          const int tap = (kh * 5 + kw) * 3 + ic;
          const float4 wv = *(const float4*)(w1 + tap * 32 + qg * 4);
          a0 += pv * wv.x; a1 += pv * wv.y; a2 += pv * wv.z; a3 += pv * wv.w;
        }
    const float a[4] = {fmaxf(a0, 0.f), fmaxf(a1, 0.f),
                        fmaxf(a2, 0.f), fmaxf(a3, 0.f)};
    const float* wr = fw0 + ((size_t)pos * 64 + 32 + qg * 4) * 32;
#pragma unroll
    for (int j = 0; j < 4; ++j) {
      const float aj = a[j];
#pragma unroll
      for (int q2 = 0; q2 < 8; ++q2) {
        const float4 wv = *(const float4*)(wr + j * 32 + q2 * 4);
        hacc[q2 * 4 + 0] += aj * wv.x; hacc[q2 * 4 + 1] += aj * wv.y;
        hacc[q2 * 4 + 2] += aj * wv.z; hacc[q2 * 4 + 3] += aj * wv.w;
      }
    }
  }

  // ---- pooled taps (TF avg_pool: normalize by valid count) ----
  float inv[3][3];
#pragma unroll
  for (int kh = 0; kh < 3; ++kh)
#pragma unroll
    for (int kw = 0; kw < 3; ++kw) {
      const int rc = 3 - ((oh == 0 && kh == 0) ? 1 : 0);
      int cc2 = 3;
      if (ow == 0 && kw == 0) cc2 = 2;
      if (ow == OWW - 1 && kw == 2) cc2 = 2;
      inv[kh][kw] = 1.0f / (float)(rc * cc2);
    }
  float pooled[27];
#pragma unroll
  for (int kh = 0; kh < 3; ++kh)
#pragma unroll
    for (int kw = 0; kw < 3; ++kw)
#pragma unroll
      for (int ic = 0; ic < 3; ++ic) {
        float s = 0.f;
#pragma unroll
        for (int dr = 0; dr < 3; ++dr)
#pragma unroll
          for (int dc = 0; dc < 3; ++dc)
            s += xv[kh + dr][(kw + dc) * 3 + ic];
        pooled[(kh * 3 + kw) * 3 + ic] = s * inv[kh][kw];
      }

  // ---- conv0 (pooled) -> feat ch 0..31, fused matvec into hacc ----
#pragma unroll 1
  for (int qg = 0; qg < 8; ++qg) {
    float a0 = 0.f, a1 = 0.f, a2 = 0.f, a3 = 0.f;
#pragma unroll
    for (int tap = 0; tap < 27; ++tap) {
      const float pv = pooled[tap];
      const float4 wv = *(const float4*)(w0 + tap * 32 + qg * 4);
      a0 += pv * wv.x; a1 += pv * wv.y; a2 += pv * wv.z; a3 += pv * wv.w;
    }
    const float a[4] = {fmaxf(a0, 0.f), fmaxf(a1, 0.f),
                        fmaxf(a2, 0.f), fmaxf(a3, 0.f)};
    const float* wr = fw0 + ((size_t)pos * 64 + qg * 4) * 32;
#pragma unroll
    for (int j = 0; j < 4; ++j) {
      const float aj = a[j];
#pragma unroll
      for (int q2 = 0; q2 < 8; ++q2) {
        const float4 wv = *(const float4*)(wr + j * 32 + q2 * 4);
        hacc[q2 * 4 + 0] += aj * wv.x; hacc[q2 * 4 + 1] += aj * wv.y;
        hacc[q2 * 4 + 2] += aj * wv.z; hacc[q2 * 4 + 3] += aj * wv.w;
      }
    }
  }

  // ---- write part[pos][n][b]: b innermost -> 256B full-line wave stores ----
  float* po = part + (size_t)pos * 32 * 512 + b;
#pragma unroll
  for (int n = 0; n < 32; ++n) po[(size_t)n * 512] = hacc[n];
}

// ---------------------------------------------------------------------------
// K2: stage-1 pos reduction: part[338][32][512] -> part2[13][32][512]
// Block = (pc, bchunk); wave og owns oc-octet; 256B coalesced loads/stores.
// ---------------------------------------------------------------------------
__global__ __launch_bounds__(256) void k_theta1(const float* __restrict__ part,
                                                float* __restrict__ part2) {
  const int pc = blockIdx.x >> 3;        // 0..12
  const int bc = blockIdx.x & 7;         // 0..7
  const int lane = threadIdx.x & 63;
  const int og = threadIdx.x >> 6;       // 0..3
  const int bcol = bc * 64 + lane;
  float acc[8] = {0.f, 0.f, 0.f, 0.f, 0.f, 0.f, 0.f, 0.f};
  const float* pp = part + ((size_t)pc * PCH * 32 + og * 8) * 512 + bcol;
  for (int pq = 0; pq < PCH; ++pq) {
#pragma unroll
    for (int j = 0; j < 8; ++j)
      acc[j] += pp[((size_t)pq * 32 + j) * 512];
  }
  float* o = part2 + ((size_t)pc * 32 + og * 8) * 512 + bcol;
#pragma unroll
  for (int j = 0; j < 8; ++j) o[(size_t)j * 512] = acc[j];
}

// ---------------------------------------------------------------------------
// K3: final reduce + bias + tanh -> hid; fc1 + tanh -> theta[512][6]
// ---------------------------------------------------------------------------
__global__ __launch_bounds__(256) void k_theta2(const float* __restrict__ part2,
                                                const float* __restrict__ b0,
                                                const float* __restrict__ w1f,
                                                const float* __restrict__ b1,
                                                float* __restrict__ theta) {
  __shared__ float hid[64][32];
  const int lane = threadIdx.x & 63;
  const int og = threadIdx.x >> 6;
  const int bcol = blockIdx.x * 64 + lane;
#pragma unroll
  for (int j = 0; j < 8; ++j) {
    const int oc = og * 8 + j;
    float s = b0[oc];
#pragma unroll
    for (int pc = 0; pc < NPC; ++pc)
      s += part2[((size_t)pc * 32 + oc) * 512 + bcol];
    hid[lane][oc] = tanhf(s);
  }
  __syncthreads();
  for (int u = threadIdx.x; u < 64 * 6; u += 256) {
    const int bl = u / 6, j = u - bl * 6;
    float s2 = b1[j];
#pragma unroll
    for (int oc = 0; oc < 32; ++oc) s2 += hid[bl][oc] * w1f[oc * 6 + j];
    theta[(blockIdx.x * 64 + bl) * 6 + j] = tanhf(s2);
  }
}

// ---------------------------------------------------------------------------
// K4: affine grid + bilinear sample (exact reference clip/extrapolate; Wd==1)
// ---------------------------------------------------------------------------
__global__ __launch_bounds__(256) void k_sample(const float* __restrict__ x,
                                                const float* __restrict__ theta,
                                                float* __restrict__ out) {
  const int b = blockIdx.x >> 3;
  const int seg = blockIdx.x & 7;
  __shared__ float th[6];
  if (threadIdx.x < 6) th[threadIdx.x] = theta[b * 6 + threadIdx.x];
  __syncthreads();
  const float t00 = th[0], t01 = th[1], t02 = th[2];
  const float t10 = th[3], t11 = th[4], t12 = th[5];
  const int idx = seg * 1024 + threadIdx.x * 4;  // pixel index within image
  const int i = idx >> 7, j0 = idx & 127;
  const float yt = (float)i * (2.0f / 63.0f) - 1.0f;
  const float* xb = x + (size_t)b * (HH * WW * CC);
  float res[12];
#pragma unroll
  for (int p = 0; p < 4; ++p) {
    const float xt = (float)(j0 + p) * (2.0f / 127.0f) - 1.0f;
    const float gx = (t00 * xt + t01 * yt + t02 + 1.0f) * 64.0f;
    const float gy = (t10 * xt + t11 * yt + t12 + 1.0f) * 32.0f;
    const float fx = floorf(gx), fy = floorf(gy);
    const float x0f = fminf(fmaxf(fx, 0.f), 126.f);
    const float x1f = fminf(fmaxf(fx + 1.f, 1.f), 127.f);
    const float y0f = fminf(fmaxf(fy, 0.f), 62.f);
    const float y1f = fminf(fmaxf(fy + 1.f, 1.f), 63.f);
    const float wx0 = x1f - gx, wx1 = gx - x0f;
    const float wy0 = y1f - gy, wy1 = gy - y0f;
    const int xi0 = (int)x0f, xi1 = (int)x1f;
    const int yi0 = (int)y0f, yi1 = (int)y1f;
    const float* q00 = xb + (yi0 * WW + xi0) * 3;
    const float* q01 = xb + (yi1 * WW + xi0) * 3;
    const float* q10 = xb + (yi0 * WW + xi1) * 3;
    const float* q11 = xb + (yi1 * WW + xi1) * 3;
#pragma unroll
    for (int c = 0; c < 3; ++c)
      res[p * 3 + c] = wx0 * (wy0 * q00[c] + wy1 * q01[c]) +
                       wx1 * (wy0 * q10[c] + wy1 * q11[c]);
  }
  float4* o = (float4*)(out + ((size_t)b * 8192 + idx) * 3);
  o[0] = make_float4(res[0], res[1], res[2], res[3]);
  o[1] = make_float4(res[4], res[5], res[6], res[7]);
  o[2] = make_float4(res[8], res[9], res[10], res[11]);
}

extern "C" void kernel_launch(void* const* d_in, const int* in_sizes, int n_in,
                              void* d_out, int out_size, void* d_ws, size_t ws_size,
                              hipStream_t stream) {
  (void)in_sizes; (void)n_in; (void)out_size; (void)ws_size;
  const float* x   = (const float*)d_in[0];
  const float* w0  = (const float*)d_in[1];
  const float* w1  = (const float*)d_in[2];
  const float* fw0 = (const float*)d_in[3];
  const float* fb0 = (const float*)d_in[4];
  const float* fw1 = (const float*)d_in[5];
  const float* fb1 = (const float*)d_in[6];
  float* outp = (float*)d_out;
  // d_out doubles as scratch: part (338*32*512 = 5,538,816 floats) +
  // part2 (13*32*512 = 212,992) = 5,751,808 <= 12,582,912 floats of d_out.
  // Fully consumed before k_sample overwrites every output element.
  float* part  = outp;
  float* part2 = outp + (size_t)NPOS * 32 * 512;
  float* theta = (float*)d_ws;  // 12 KB — survives k_sample's output writes
  k_locnet<<<NPOS * 2, 256, 0, stream>>>(x, w0, w1, fw0, part);
  k_theta1<<<NPC * 8, 256, 0, stream>>>(part, part2);
  k_theta2<<<8, 256, 0, stream>>>(part2, fb0, fw1, fb1, theta);
  k_sample<<<BN * 8, 256, 0, stream>>>(x, theta, outp);
}

// Round 11
// 138.781 us; speedup vs baseline: 1.0240x; 1.0240x over previous
//
#include <hip/hip_runtime.h>
#include <math.h>

namespace {
constexpr int BN = 512, HH = 64, WW = 128, CC = 3;
constexpr int OHH = 13, OWW = 26;
constexpr int NPOS = OHH * OWW;   // 338
constexpr int PCH = 26;           // pos per theta1 chunk
constexpr int NPC = NPOS / PCH;   // 13
}

// ---------------------------------------------------------------------------
// K1: fused LocNet front end + fc0 partial.
// Per thread (pos,b): avgpool+conv0+relu and conv1+relu entirely in registers,
// then matvec the 64 feat values into hacc[32] with fc0 rows pos*64+ch
// (pos uniform -> s_load). __launch_bounds__(256,2) lifts the VGPR cap so
// xv[90]+hacc[32]+pooled[27] stay register-resident (at VGPR=76 the compiler
// rematerialized x loads inside the loops -> FETCH 95MB for a 50MB input).
// Valid footprint rows are ri in [ri_lo, ri_hi] (BOTH bounds: oh==0 clips the
// top row, oh==12 clips the bottom row r0+5==64 — R10 missed this -> OOB).
// ---------------------------------------------------------------------------
__global__ __launch_bounds__(256, 2) void k_locnet(const float* __restrict__ x,
                                                   const float* __restrict__ w0,
                                                   const float* __restrict__ w1,
                                                   const float* __restrict__ fw0,
                                                   float* __restrict__ part) {
  const int pos = blockIdx.x >> 1;                       // uniform per block
  const int b = ((blockIdx.x & 1) << 8) + threadIdx.x;   // 0..511
  const int oh = pos / 26;
  const int ow = pos - oh * 26;
  const float* xb = x + (size_t)b * (HH * WW * CC);

  // footprint rows r0..r0+5 (r0 = oh*5-1), 15 floats per row.
  const int r0 = oh * 5 - 1;
  const int ri_lo = (oh == 0) ? 1 : 0;        // row -1 invalid at top
  const int ri_hi = (oh == OHH - 1) ? 4 : 5;  // row 64 invalid at bottom
  float xv[6][15];
  if (ow > 0 && ow < OWW - 1) {
    // interior columns: no column clipping; all loads issued up-front.
    float4 q[6][4];
#pragma unroll
    for (int ri = 0; ri < 6; ++ri) {
      if (ri >= ri_lo && ri <= ri_hi) {  // uniform condition
        const float* rp = xb + (size_t)(r0 + ri) * (WW * CC) + (ow * 5 - 1) * 3;
        q[ri][0] = *(const float4*)(rp);
        q[ri][1] = *(const float4*)(rp + 4);
        q[ri][2] = *(const float4*)(rp + 8);
        q[ri][3] = *(const float4*)(rp + 12);  // elem 15 unused
      }
    }
#pragma unroll
    for (int ri = 0; ri < 6; ++ri) {
      if (ri < ri_lo || ri > ri_hi) {
#pragma unroll
        for (int c = 0; c < 15; ++c) xv[ri][c] = 0.f;
      } else {
        xv[ri][0] = q[ri][0].x; xv[ri][1] = q[ri][0].y; xv[ri][2] = q[ri][0].z;
        xv[ri][3] = q[ri][0].w; xv[ri][4] = q[ri][1].x; xv[ri][5] = q[ri][1].y;
        xv[ri][6] = q[ri][1].z; xv[ri][7] = q[ri][1].w; xv[ri][8] = q[ri][2].x;
        xv[ri][9] = q[ri][2].y; xv[ri][10] = q[ri][2].z; xv[ri][11] = q[ri][2].w;
        xv[ri][12] = q[ri][3].x; xv[ri][13] = q[ri][3].y; xv[ri][14] = q[ri][3].z;
      }
    }
  } else {
    // edge columns (ow==0 or ow==25): per-element clip path (uniform branch)
#pragma unroll
    for (int ri = 0; ri < 6; ++ri) {
      const int gr = r0 + ri;
      const int grc = min(max(gr, 0), HH - 1);
      const bool rv = (gr >= 0) & (gr <= HH - 1);
      const float* rowp = xb + grc * (WW * CC);
#pragma unroll
      for (int pj = 0; pj < 5; ++pj) {
        const int gc = ow * 5 - 1 + pj;
        const int gcc = min(max(gc, 0), WW - 1);
        const bool v = rv & (gc >= 0) & (gc <= WW - 1);
        const float* pp = rowp + gcc * CC;
        const float f0 = pp[0], f1 = pp[1], f2 = pp[2];
        xv[ri][pj * 3 + 0] = v ? f0 : 0.f;
        xv[ri][pj * 3 + 1] = v ? f1 : 0.f;
        xv[ri][pj * 3 + 2] = v ? f2 : 0.f;
      }
    }
  }

  float hacc[32];
#pragma unroll
  for (int n = 0; n < 32; ++n) hacc[n] = 0.f;

  // ---- conv1 (raw x) -> feat ch 32..63, fused matvec into hacc ----
#pragma unroll 1
  for (int qg = 0; qg < 8; ++qg) {
    float a0 = 0.f, a1 = 0.f, a2 = 0.f, a3 = 0.f;
#pragma unroll
    for (int kh = 0; kh < 5; ++kh)
#pragma unroll
      for (int kw = 0; kw < 5; ++kw)
#pragma unroll
        for (int ic = 0; ic < 3; ++ic) {
          const float pv = xv[kh + 1][kw * 3 + ic];
          const int tap = (kh * 5 + kw) * 3 + ic;
          const float4 wv = *(const float4*)(w1 + tap * 32 + qg * 4);
          a0 += pv * wv.x; a1 += pv * wv.y; a2 += pv * wv.z; a3 += pv * wv.w;
        }
    const float a[4] = {fmaxf(a0, 0.f), fmaxf(a1, 0.f),
                        fmaxf(a2, 0.f), fmaxf(a3, 0.f)};
    const float* wr = fw0 + ((size_t)pos * 64 + 32 + qg * 4) * 32;
#pragma unroll
    for (int j = 0; j < 4; ++j) {
      const float aj = a[j];
#pragma unroll
      for (int q2 = 0; q2 < 8; ++q2) {
        const float4 wv = *(const float4*)(wr + j * 32 + q2 * 4);
        hacc[q2 * 4 + 0] += aj * wv.x; hacc[q2 * 4 + 1] += aj * wv.y;
        hacc[q2 * 4 + 2] += aj * wv.z; hacc[q2 * 4 + 3] += aj * wv.w;
      }
    }
  }

  // ---- pooled taps (TF avg_pool: normalize by valid count) ----
  float inv[3][3];
#pragma unroll
  for (int kh = 0; kh < 3; ++kh)
#pragma unroll
    for (int kw = 0; kw < 3; ++kw) {
      const int rc = 3 - ((oh == 0 && kh == 0) ? 1 : 0);
      int cc2 = 3;
      if (ow == 0 && kw == 0) cc2 = 2;
      if (ow == OWW - 1 && kw == 2) cc2 = 2;
      inv[kh][kw] = 1.0f / (float)(rc * cc2);
    }
  float pooled[27];
#pragma unroll
  for (int kh = 0; kh < 3; ++kh)
#pragma unroll
    for (int kw = 0; kw < 3; ++kw)
#pragma unroll
      for (int ic = 0; ic < 3; ++ic) {
        float s = 0.f;
#pragma unroll
        for (int dr = 0; dr < 3; ++dr)
#pragma unroll
          for (int dc = 0; dc < 3; ++dc)
            s += xv[kh + dr][(kw + dc) * 3 + ic];
        pooled[(kh * 3 + kw) * 3 + ic] = s * inv[kh][kw];
      }

  // ---- conv0 (pooled) -> feat ch 0..31, fused matvec into hacc ----
#pragma unroll 1
  for (int qg = 0; qg < 8; ++qg) {
    float a0 = 0.f, a1 = 0.f, a2 = 0.f, a3 = 0.f;
#pragma unroll
    for (int tap = 0; tap < 27; ++tap) {
      const float pv = pooled[tap];
      const float4 wv = *(const float4*)(w0 + tap * 32 + qg * 4);
      a0 += pv * wv.x; a1 += pv * wv.y; a2 += pv * wv.z; a3 += pv * wv.w;
    }
    const float a[4] = {fmaxf(a0, 0.f), fmaxf(a1, 0.f),
                        fmaxf(a2, 0.f), fmaxf(a3, 0.f)};
    const float* wr = fw0 + ((size_t)pos * 64 + qg * 4) * 32;
#pragma unroll
    for (int j = 0; j < 4; ++j) {
      const float aj = a[j];
#pragma unroll
      for (int q2 = 0; q2 < 8; ++q2) {
        const float4 wv = *(const float4*)(wr + j * 32 + q2 * 4);
        hacc[q2 * 4 + 0] += aj * wv.x; hacc[q2 * 4 + 1] += aj * wv.y;
        hacc[q2 * 4 + 2] += aj * wv.z; hacc[q2 * 4 + 3] += aj * wv.w;
      }
    }
  }

  // ---- write part[pos][n][b]: b innermost -> 256B full-line wave stores ----
  float* po = part + (size_t)pos * 32 * 512 + b;
#pragma unroll
  for (int n = 0; n < 32; ++n) po[(size_t)n * 512] = hacc[n];
}

// ---------------------------------------------------------------------------
// K2: stage-1 pos reduction: part[338][32][512] -> part2[13][32][512]
// ---------------------------------------------------------------------------
__global__ __launch_bounds__(256) void k_theta1(const float* __restrict__ part,
                                                float* __restrict__ part2) {
  const int pc = blockIdx.x >> 3;        // 0..12
  const int bc = blockIdx.x & 7;         // 0..7
  const int lane = threadIdx.x & 63;
  const int og = threadIdx.x >> 6;       // 0..3
  const int bcol = bc * 64 + lane;
  float acc[8] = {0.f, 0.f, 0.f, 0.f, 0.f, 0.f, 0.f, 0.f};
  const float* pp = part + ((size_t)pc * PCH * 32 + og * 8) * 512 + bcol;
  for (int pq = 0; pq < PCH; ++pq) {
#pragma unroll
    for (int j = 0; j < 8; ++j)
      acc[j] += pp[((size_t)pq * 32 + j) * 512];
  }
  float* o = part2 + ((size_t)pc * 32 + og * 8) * 512 + bcol;
#pragma unroll
  for (int j = 0; j < 8; ++j) o[(size_t)j * 512] = acc[j];
}

// ---------------------------------------------------------------------------
// K3: final reduce + bias + tanh -> hid; fc1 + tanh -> theta[512][6]
// ---------------------------------------------------------------------------
__global__ __launch_bounds__(256) void k_theta2(const float* __restrict__ part2,
                                                const float* __restrict__ b0,
                                                const float* __restrict__ w1f,
                                                const float* __restrict__ b1,
                                                float* __restrict__ theta) {
  __shared__ float hid[64][32];
  const int lane = threadIdx.x & 63;
  const int og = threadIdx.x >> 6;
  const int bcol = blockIdx.x * 64 + lane;
#pragma unroll
  for (int j = 0; j < 8; ++j) {
    const int oc = og * 8 + j;
    float s = b0[oc];
#pragma unroll
    for (int pc = 0; pc < NPC; ++pc)
      s += part2[((size_t)pc * 32 + oc) * 512 + bcol];
    hid[lane][oc] = tanhf(s);
  }
  __syncthreads();
  for (int u = threadIdx.x; u < 64 * 6; u += 256) {
    const int bl = u / 6, j = u - bl * 6;
    float s2 = b1[j];
#pragma unroll
    for (int oc = 0; oc < 32; ++oc) s2 += hid[bl][oc] * w1f[oc * 6 + j];
    theta[(blockIdx.x * 64 + bl) * 6 + j] = tanhf(s2);
  }
}

// ---------------------------------------------------------------------------
// K4: affine grid + bilinear sample (exact reference clip/extrapolate; Wd==1)
// ---------------------------------------------------------------------------
__global__ __launch_bounds__(256) void k_sample(const float* __restrict__ x,
                                                const float* __restrict__ theta,
                                                float* __restrict__ out) {
  const int b = blockIdx.x >> 3;
  const int seg = blockIdx.x & 7;
  __shared__ float th[6];
  if (threadIdx.x < 6) th[threadIdx.x] = theta[b * 6 + threadIdx.x];
  __syncthreads();
  const float t00 = th[0], t01 = th[1], t02 = th[2];
  const float t10 = th[3], t11 = th[4], t12 = th[5];
  const int idx = seg * 1024 + threadIdx.x * 4;  // pixel index within image
  const int i = idx >> 7, j0 = idx & 127;
  const float yt = (float)i * (2.0f / 63.0f) - 1.0f;
  const float* xb = x + (size_t)b * (HH * WW * CC);
  float res[12];
#pragma unroll
  for (int p = 0; p < 4; ++p) {
    const float xt = (float)(j0 + p) * (2.0f / 127.0f) - 1.0f;
    const float gx = (t00 * xt + t01 * yt + t02 + 1.0f) * 64.0f;
    const float gy = (t10 * xt + t11 * yt + t12 + 1.0f) * 32.0f;
    const float fx = floorf(gx), fy = floorf(gy);
    const float x0f = fminf(fmaxf(fx, 0.f), 126.f);
    const float x1f = fminf(fmaxf(fx + 1.f, 1.f), 127.f);
    const float y0f = fminf(fmaxf(fy, 0.f), 62.f);
    const float y1f = fminf(fmaxf(fy + 1.f, 1.f), 63.f);
    const float wx0 = x1f - gx, wx1 = gx - x0f;
    const float wy0 = y1f - gy, wy1 = gy - y0f;
    const int xi0 = (int)x0f, xi1 = (int)x1f;
    const int yi0 = (int)y0f, yi1 = (int)y1f;
    const float* q00 = xb + (yi0 * WW + xi0) * 3;
    const float* q01 = xb + (yi1 * WW + xi0) * 3;
    const float* q10 = xb + (yi0 * WW + xi1) * 3;
    const float* q11 = xb + (yi1 * WW + xi1) * 3;
#pragma unroll
    for (int c = 0; c < 3; ++c)
      res[p * 3 + c] = wx0 * (wy0 * q00[c] + wy1 * q01[c]) +
                       wx1 * (wy0 * q10[c] + wy1 * q11[c]);
  }
  float4* o = (float4*)(out + ((size_t)b * 8192 + idx) * 3);
  o[0] = make_float4(res[0], res[1], res[2], res[3]);
  o[1] = make_float4(res[4], res[5], res[6], res[7]);
  o[2] = make_float4(res[8], res[9], res[10], res[11]);
}

extern "C" void kernel_launch(void* const* d_in, const int* in_sizes, int n_in,
                              void* d_out, int out_size, void* d_ws, size_t ws_size,
                              hipStream_t stream) {
  (void)in_sizes; (void)n_in; (void)out_size; (void)ws_size;
  const float* x   = (const float*)d_in[0];
  const float* w0  = (const float*)d_in[1];
  const float* w1  = (const float*)d_in[2];
  const float* fw0 = (const float*)d_in[3];
  const float* fb0 = (const float*)d_in[4];
  const float* fw1 = (const float*)d_in[5];
  const float* fb1 = (const float*)d_in[6];
  float* outp = (float*)d_out;
  // d_out doubles as scratch: part (338*32*512 = 5,538,816 floats) +
  // part2 (13*32*512 = 212,992) = 5,751,808 <= 12,582,912 floats of d_out.
  // Fully consumed before k_sample overwrites every output element.
  float* part  = outp;
  float* part2 = outp + (size_t)NPOS * 32 * 512;
  float* theta = (float*)d_ws;  // 12 KB — survives k_sample's output writes
  k_locnet<<<NPOS * 2, 256, 0, stream>>>(x, w0, w1, fw0, part);
  k_theta1<<<NPC * 8, 256, 0, stream>>>(part, part2);
  k_theta2<<<8, 256, 0, stream>>>(part2, fb0, fw1, fb1, theta);
  k_sample<<<BN * 8, 256, 0, stream>>>(x, theta, outp);
}

// Round 13
// 136.846 us; speedup vs baseline: 1.0385x; 1.0141x over previous
//
#include <hip/hip_runtime.h>
#include <math.h>

namespace {
constexpr int BN = 512, HH = 64, WW = 128, CC = 3;
constexpr int OHH = 13, OWW = 26;
constexpr int NPOS = OHH * OWW;   // 338
constexpr int NSLAB = NPOS * 2;   // 676 partial slabs (pos x role)
constexpr int PCH = 26;           // slabs per theta1 chunk
constexpr int NPC = NSLAB / PCH;  // 26
}

// ---------------------------------------------------------------------------
// K1: fused LocNet front end + fc0 partial, ROLE-SPLIT:
//   role 0 (waves 0-1): avgpool(count-norm)+conv0(3x3,s5)+relu -> ch 0..31
//   role 1 (waves 2-3): conv1(5x5,s5)+relu                     -> ch 32..63
// Each role needs only 5 rows x 15 floats and ~half the FMA of R11's thread,
// then matvecs its 32 feat values into hacc[32] via fc0 rows (pos uniform ->
// s_load) and writes slab part[pos*2+role][n][b] (b innermost, 256B lines).
// Grid = 4 b-chunks x 338 pos = 1352 blocks (5.3 waves/SIMD vs R11's 2.6).
// Bijective XCD swizzle, bc-major: each XCD gets 169 pos-contiguous blocks of
// one b-chunk -> ~3MB working set fits its 4MB L2 -> pos-overlap reads hit L2.
// ---------------------------------------------------------------------------
__global__ __launch_bounds__(256) void k_locnet(const float* __restrict__ x,
                                                const float* __restrict__ w0,
                                                const float* __restrict__ w1,
                                                const float* __restrict__ fw0,
                                                float* __restrict__ part) {
  const int cpx = (NPOS * 4) >> 3;                      // 169
  const int L = (blockIdx.x & 7) * cpx + (blockIdx.x >> 3);
  const int bc = L / NPOS;                              // 0..3 (b-chunk)
  const int pos = L - bc * NPOS;                        // 0..337
  const int oh = pos / OWW, ow = pos - oh * OWW;
  const int role = threadIdx.x >> 7;                    // wave-uniform
  const int b = bc * 128 + (threadIdx.x & 127);
  const float* xb = x + (size_t)b * (HH * WW * CC);

  // footprint rows rbase..rbase+4, cols ow*5-1 .. ow*5+3 (15 floats)
  const int rbase = oh * 5 - 1 + role;
  float xv[5][15];
  if (ow > 0 && ow < OWW - 1) {
    float4 q[5][4];
#pragma unroll
    for (int ri = 0; ri < 5; ++ri) {
      const int gr = rbase + ri;
      if (gr >= 0 && gr < HH) {  // uniform
        const float* rp = xb + (size_t)gr * (WW * CC) + (ow * 5 - 1) * 3;
        q[ri][0] = *(const float4*)(rp);
        q[ri][1] = *(const float4*)(rp + 4);
        q[ri][2] = *(const float4*)(rp + 8);
        q[ri][3] = *(const float4*)(rp + 12);  // 16th elem unused
      }
    }
#pragma unroll
    for (int ri = 0; ri < 5; ++ri) {
      const int gr = rbase + ri;
      if (gr < 0 || gr >= HH) {
#pragma unroll
        for (int c = 0; c < 15; ++c) xv[ri][c] = 0.f;
      } else {
        xv[ri][0] = q[ri][0].x; xv[ri][1] = q[ri][0].y; xv[ri][2] = q[ri][0].z;
        xv[ri][3] = q[ri][0].w; xv[ri][4] = q[ri][1].x; xv[ri][5] = q[ri][1].y;
        xv[ri][6] = q[ri][1].z; xv[ri][7] = q[ri][1].w; xv[ri][8] = q[ri][2].x;
        xv[ri][9] = q[ri][2].y; xv[ri][10] = q[ri][2].z; xv[ri][11] = q[ri][2].w;
        xv[ri][12] = q[ri][3].x; xv[ri][13] = q[ri][3].y; xv[ri][14] = q[ri][3].z;
      }
    }
  } else {
    // ow==0 or ow==25: per-element clip path (uniform branch)
#pragma unroll
    for (int ri = 0; ri < 5; ++ri) {
      const int gr = rbase + ri;
      const int grc = min(max(gr, 0), HH - 1);
      const bool rv = (gr >= 0) & (gr < HH);
      const float* rowp = xb + grc * (WW * CC);
#pragma unroll
      for (int c = 0; c < 5; ++c) {
        const int gc = ow * 5 - 1 + c;
        const int gcc = min(max(gc, 0), WW - 1);
        const bool v = rv & (gc >= 0) & (gc < WW);
        const float* pp = rowp + gcc * CC;
        const float f0 = pp[0], f1 = pp[1], f2 = pp[2];
        xv[ri][c * 3 + 0] = v ? f0 : 0.f;
        xv[ri][c * 3 + 1] = v ? f1 : 0.f;
        xv[ri][c * 3 + 2] = v ? f2 : 0.f;
      }
    }
  }

  float hacc[32];
#pragma unroll
  for (int n = 0; n < 32; ++n) hacc[n] = 0.f;

  if (role == 0) {
    // ---- avgpool (exact valid-count norm) + conv0 + relu + matvec ----
    float pooled[27];
#pragma unroll
    for (int kh = 0; kh < 3; ++kh)
#pragma unroll
      for (int kw = 0; kw < 3; ++kw) {
        const int gr = oh * 5 + kh, gc = ow * 5 + kw;
        const int rc = min(gr + 1, HH - 1) - max(gr - 1, 0) + 1;
        const int c2 = min(gc + 1, WW - 1) - max(gc - 1, 0) + 1;
        const float inv = 1.0f / (float)(rc * c2);
#pragma unroll
        for (int ic = 0; ic < 3; ++ic) {
          float s = 0.f;
#pragma unroll
          for (int dr = 0; dr < 3; ++dr)
#pragma unroll
            for (int dc = 0; dc < 3; ++dc)
              s += xv[kh + dr][(kw + dc) * 3 + ic];
          pooled[(kh * 3 + kw) * 3 + ic] = s * inv;
        }
      }
#pragma unroll 1
    for (int qg = 0; qg < 8; ++qg) {
      float a0 = 0.f, a1 = 0.f, a2 = 0.f, a3 = 0.f;
#pragma unroll
      for (int tap = 0; tap < 27; ++tap) {
        const float pv = pooled[tap];
        const float4 wv = *(const float4*)(w0 + tap * 32 + qg * 4);
        a0 += pv * wv.x; a1 += pv * wv.y; a2 += pv * wv.z; a3 += pv * wv.w;
      }
      const float a[4] = {fmaxf(a0, 0.f), fmaxf(a1, 0.f),
                          fmaxf(a2, 0.f), fmaxf(a3, 0.f)};
      const float* wr = fw0 + ((size_t)pos * 64 + qg * 4) * 32;
#pragma unroll
      for (int j = 0; j < 4; ++j) {
        const float aj = a[j];
#pragma unroll
        for (int q2 = 0; q2 < 8; ++q2) {
          const float4 wv = *(const float4*)(wr + j * 32 + q2 * 4);
          hacc[q2 * 4 + 0] += aj * wv.x; hacc[q2 * 4 + 1] += aj * wv.y;
          hacc[q2 * 4 + 2] += aj * wv.z; hacc[q2 * 4 + 3] += aj * wv.w;
        }
      }
    }
  } else {
    // ---- conv1 + relu + matvec (feat ch 32..63) ----
#pragma unroll 1
    for (int qg = 0; qg < 8; ++qg) {
      float a0 = 0.f, a1 = 0.f, a2 = 0.f, a3 = 0.f;
#pragma unroll
      for (int kh = 0; kh < 5; ++kh)
#pragma unroll
        for (int kw = 0; kw < 5; ++kw)
#pragma unroll
          for (int ic = 0; ic < 3; ++ic) {
            const float pv = xv[kh][kw * 3 + ic];
            const int tap = (kh * 5 + kw) * 3 + ic;
            const float4 wv = *(const float4*)(w1 + tap * 32 + qg * 4);
            a0 += pv * wv.x; a1 += pv * wv.y; a2 += pv * wv.z; a3 += pv * wv.w;
          }
      const float a[4] = {fmaxf(a0, 0.f), fmaxf(a1, 0.f),
                          fmaxf(a2, 0.f), fmaxf(a3, 0.f)};
      const float* wr = fw0 + ((size_t)pos * 64 + 32 + qg * 4) * 32;
#pragma unroll
      for (int j = 0; j < 4; ++j) {
        const float aj = a[j];
#pragma unroll
        for (int q2 = 0; q2 < 8; ++q2) {
          const float4 wv = *(const float4*)(wr + j * 32 + q2 * 4);
          hacc[q2 * 4 + 0] += aj * wv.x; hacc[q2 * 4 + 1] += aj * wv.y;
          hacc[q2 * 4 + 2] += aj * wv.z; hacc[q2 * 4 + 3] += aj * wv.w;
        }
      }
    }
  }

  // ---- write slab part[pos*2+role][n][b]: 256B full-line wave stores ----
  float* po = part + (size_t)(pos * 2 + role) * 32 * 512 + b;
#pragma unroll
  for (int n = 0; n < 32; ++n) po[(size_t)n * 512] = hacc[n];
}

// ---------------------------------------------------------------------------
// K2: stage-1 slab reduction: part[676][32][512] -> part2[26][32][512]
// ---------------------------------------------------------------------------
__global__ __launch_bounds__(256) void k_theta1(const float* __restrict__ part,
                                                float* __restrict__ part2) {
  const int pc = blockIdx.x >> 3;        // 0..25
  const int bcs = blockIdx.x & 7;        // 0..7
  const int lane = threadIdx.x & 63;
  const int og = threadIdx.x >> 6;       // 0..3
  const int bcol = bcs * 64 + lane;
  float acc[8] = {0.f, 0.f, 0.f, 0.f, 0.f, 0.f, 0.f, 0.f};
  const float* pp = part + ((size_t)pc * PCH * 32 + og * 8) * 512 + bcol;
  for (int pq = 0; pq < PCH; ++pq) {
#pragma unroll
    for (int j = 0; j < 8; ++j)
      acc[j] += pp[((size_t)pq * 32 + j) * 512];
  }
  float* o = part2 + ((size_t)pc * 32 + og * 8) * 512 + bcol;
#pragma unroll
  for (int j = 0; j < 8; ++j) o[(size_t)j * 512] = acc[j];
}

// ---------------------------------------------------------------------------
// K3: final reduce + bias + tanh -> hid; fc1 + tanh -> theta[512][6]
// ---------------------------------------------------------------------------
__global__ __launch_bounds__(256) void k_theta2(const float* __restrict__ part2,
                                                const float* __restrict__ b0,
                                                const float* __restrict__ w1f,
                                                const float* __restrict__ b1,
                                                float* __restrict__ theta) {
  __shared__ float hid[64][32];
  const int lane = threadIdx.x & 63;
  const int og = threadIdx.x >> 6;
  const int bcol = blockIdx.x * 64 + lane;
#pragma unroll
  for (int j = 0; j < 8; ++j) {
    const int oc = og * 8 + j;
    float s = b0[oc];
#pragma unroll
    for (int pc = 0; pc < NPC; ++pc)
      s += part2[((size_t)pc * 32 + oc) * 512 + bcol];
    hid[lane][oc] = tanhf(s);
  }
  __syncthreads();
  for (int u = threadIdx.x; u < 64 * 6; u += 256) {
    const int bl = u / 6, j = u - bl * 6;
    float s2 = b1[j];
#pragma unroll
    for (int oc = 0; oc < 32; ++oc) s2 += hid[bl][oc] * w1f[oc * 6 + j];
    theta[(blockIdx.x * 64 + bl) * 6 + j] = tanhf(s2);
  }
}

// ---------------------------------------------------------------------------
// K4: affine grid + bilinear sample (exact reference clip/extrapolate; Wd==1)
// ---------------------------------------------------------------------------
__global__ __launch_bounds__(256) void k_sample(const float* __restrict__ x,
                                                const float* __restrict__ theta,
                                                float* __restrict__ out) {
  const int b = blockIdx.x >> 3;
  const int seg = blockIdx.x & 7;
  __shared__ float th[6];
  if (threadIdx.x < 6) th[threadIdx.x] = theta[b * 6 + threadIdx.x];
  __syncthreads();
  const float t00 = th[0], t01 = th[1], t02 = th[2];
  const float t10 = th[3], t11 = th[4], t12 = th[5];
  const int idx = seg * 1024 + threadIdx.x * 4;  // pixel index within image
  const int i = idx >> 7, j0 = idx & 127;
  const float yt = (float)i * (2.0f / 63.0f) - 1.0f;
  const float* xb = x + (size_t)b * (HH * WW * CC);
  float res[12];
#pragma unroll
  for (int p = 0; p < 4; ++p) {
    const float xt = (float)(j0 + p) * (2.0f / 127.0f) - 1.0f;
    const float gx = (t00 * xt + t01 * yt + t02 + 1.0f) * 64.0f;
    const float gy = (t10 * xt + t11 * yt + t12 + 1.0f) * 32.0f;
    const float fx = floorf(gx), fy = floorf(gy);
    const float x0f = fminf(fmaxf(fx, 0.f), 126.f);
    const float x1f = fminf(fmaxf(fx + 1.f, 1.f), 127.f);
    const float y0f = fminf(fmaxf(fy, 0.f), 62.f);
    const float y1f = fminf(fmaxf(fy + 1.f, 1.f), 63.f);
    const float wx0 = x1f - gx, wx1 = gx - x0f;
    const float wy0 = y1f - gy, wy1 = gy - y0f;
    const int xi0 = (int)x0f, xi1 = (int)x1f;
    const int yi0 = (int)y0f, yi1 = (int)y1f;
    const float* q00 = xb + (yi0 * WW + xi0) * 3;
    const float* q01 = xb + (yi1 * WW + xi0) * 3;
    const float* q10 = xb + (yi0 * WW + xi1) * 3;
    const float* q11 = xb + (yi1 * WW + xi1) * 3;
#pragma unroll
    for (int c = 0; c < 3; ++c)
      res[p * 3 + c] = wx0 * (wy0 * q00[c] + wy1 * q01[c]) +
                       wx1 * (wy0 * q10[c] + wy1 * q11[c]);
  }
  float4* o = (float4*)(out + ((size_t)b * 8192 + idx) * 3);
  o[0] = make_float4(res[0], res[1], res[2], res[3]);
  o[1] = make_float4(res[4], res[5], res[6], res[7]);
  o[2] = make_float4(res[8], res[9], res[10], res[11]);
}

extern "C" void kernel_launch(void* const* d_in, const int* in_sizes, int n_in,
                              void* d_out, int out_size, void* d_ws, size_t ws_size,
                              hipStream_t stream) {
  (void)in_sizes; (void)n_in; (void)out_size; (void)ws_size;
  const float* x   = (const float*)d_in[0];
  const float* w0  = (const float*)d_in[1];
  const float* w1  = (const float*)d_in[2];
  const float* fw0 = (const float*)d_in[3];
  const float* fb0 = (const float*)d_in[4];
  const float* fw1 = (const float*)d_in[5];
  const float* fb1 = (const float*)d_in[6];
  float* outp = (float*)d_out;
  // d_out doubles as scratch: part (676*32*512 = 11,075,584 floats) +
  // part2 (26*32*512 = 425,984) = 11,501,568 <= 12,582,912 floats of d_out.
  // Fully consumed before k_sample overwrites every output element.
  float* part  = outp;
  float* part2 = outp + (size_t)NSLAB * 32 * 512;
  float* theta = (float*)d_ws;  // 12 KB — survives k_sample's output writes
  k_locnet<<<NPOS * 4, 256, 0, stream>>>(x, w0, w1, fw0, part);
  k_theta1<<<NPC * 8, 256, 0, stream>>>(part, part2);
  k_theta2<<<8, 256, 0, stream>>>(part2, fb0, fw1, fb1, theta);
  k_sample<<<BN * 8, 256, 0, stream>>>(x, theta, outp);
}